// Round 2
// baseline (2454.834 us; speedup 1.0000x reference)
//
#include <hip/hip_runtime.h>

// 2-layer LSTM recurrence, B=2048, T=1024 + future=64. One batch element per
// 128-thread block (2 waves). Lane j of wave q owns LSTM1 gate rows
// {q==0: i(j), g(102+j); q==1: f(51+j), o(153+j)}; the two rows' W_hh1 weights
// are interleaved per-lane as float2 wAB[51] so the dot product runs as
// v_pk_fma_f32 (packed dual-fp32, the only way to MI355X's 157 TF fp32).
// h1[j] lives in lane j and is broadcast via v_readlane (VALU/SALU, keeps the
// LDS pipe free). Gate activations cross waves through double-buffered LDS
// in GATE-MAJOR layout act[2][4][64] (lane-consecutive => conflict-free);
// one barrier per step. c1/h1 update + all of LSTM2 are computed redundantly
// in both waves so h2/c2 stay replicated (no 2nd barrier).
//
// __launch_bounds__(128,3): VGPR cap ~170 so the 102 weight VGPRs stay
// RESIDENT. Round-1's (128,4) cap of 128 made the compiler spill everything
// (VGPR_Count=64, ~2.4 ms). Residency is the whole ballgame here.

#define H1N 51
#define WAVE 64

typedef float v2f __attribute__((ext_vector_type(2)));

__device__ __forceinline__ float fast_sigmoid(float x) {
    return __builtin_amdgcn_rcpf(1.0f + __expf(-x));
}
__device__ __forceinline__ float fast_tanh(float x) {
    float e = __expf(2.0f * x);
    return 1.0f - 2.0f * __builtin_amdgcn_rcpf(e + 1.0f);
}

__global__ __launch_bounds__(128, 3)
void lstm_seq(const float* __restrict__ input,   // [B, T]
              const float* __restrict__ W_ih1,   // [204, 1]
              const float* __restrict__ W_hh1,   // [204, 51]
              const float* __restrict__ b_ih1,   // [204]
              const float* __restrict__ b_hh1,   // [204]
              const float* __restrict__ W_ih2,   // [4, 51]
              const float* __restrict__ W_hh2,   // [4, 1]
              const float* __restrict__ b_ih2,   // [4]
              const float* __restrict__ b_hh2,   // [4]
              float* __restrict__ out,           // [B, T+F]
              int T, int TF)
{
    const int tid = threadIdx.x;
    const int wv  = tid >> 6;          // wave id: 0 or 1
    const int j   = tid & (WAVE - 1);  // lane id
    const bool jv = (j < H1N);
    const int b   = blockIdx.x;

    // Gate rows owned by this lane (gate order i,f,g,o):
    const int rowA = wv ? (H1N + j)   : j;            // f : i
    const int rowB = wv ? (3*H1N + j) : (2*H1N + j);  // o : g

    // Interleaved per-lane weights: wAB[k] = (W_hh1[rowA][k], W_hh1[rowB][k]).
    v2f wAB[H1N];
#pragma unroll
    for (int k = 0; k < H1N; ++k) {
        wAB[k].x = jv ? W_hh1[rowA*H1N + k] : 0.0f;
        wAB[k].y = jv ? W_hh1[rowB*H1N + k] : 0.0f;
    }
    v2f bAB, wxAB;
    bAB.x  = jv ? (b_ih1[rowA] + b_hh1[rowA]) : 0.0f;
    bAB.y  = jv ? (b_ih1[rowB] + b_hh1[rowB]) : 0.0f;
    wxAB.x = jv ? W_ih1[rowA] : 0.0f;
    wxAB.y = jv ? W_ih1[rowB] : 0.0f;

    // LSTM2 (H2=1): computed redundantly by both waves.
    float wi2[4];
#pragma unroll
    for (int q = 0; q < 4; ++q) wi2[q] = jv ? W_ih2[q*H1N + j] : 0.0f;
    float whh2[4], b2[4];  // thread-uniform -> SGPRs
#pragma unroll
    for (int q = 0; q < 4; ++q) { whh2[q] = W_hh2[q]; b2[q] = b_ih2[q] + b_hh2[q]; }

    // Gate-major, lane-consecutive => conflict-free. [parity][gate][unit]
    __shared__ float act[2][4][WAVE];

    float h1 = 0.0f, c1 = 0.0f, h2 = 0.0f, c2 = 0.0f;

    const float* __restrict__ xrow = input + (long)b * T;
    float*       __restrict__ orow = out   + (long)b * TF;

    float xc = xrow[0];  // prefetched x for step t

    for (int t = 0; t < TF; ++t) {
        // Prefetch next x early (uniform s_load; consumed next iteration).
        const int tn = (t + 1 < T) ? (t + 1) : (T - 1);
        float xn = xrow[tn];

        const float x = (t < T) ? xc : h2;

        // ---- Phase 1: packed gate dots; h1 broadcast via v_readlane ----
        // Two independent chains (even/odd k) to cover FMA latency.
        v2f accE = bAB + wxAB * x;
        v2f accO = {0.0f, 0.0f};
#pragma unroll
        for (int k = 0; k + 1 < H1N; k += 2) {
            float hE = __int_as_float(__builtin_amdgcn_readlane(__float_as_int(h1), k));
            float hO = __int_as_float(__builtin_amdgcn_readlane(__float_as_int(h1), k + 1));
            accE += wAB[k]     * hE;   // v_pk_fma_f32
            accO += wAB[k + 1] * hO;
        }
        {
            float hL = __int_as_float(__builtin_amdgcn_readlane(__float_as_int(h1), H1N - 1));
            accE += wAB[H1N - 1] * hL;
        }
        const v2f acc = accE + accO;

        float aA, aB;
        if (wv == 0) { aA = fast_sigmoid(acc.x); aB = fast_tanh(acc.y); }    // i, g
        else         { aA = fast_sigmoid(acc.x); aB = fast_sigmoid(acc.y); } // f, o

        const int p = t & 1;
        act[p][wv][j]     = aA;   // wave0 -> i, wave1 -> f
        act[p][wv + 2][j] = aB;   // wave0 -> g, wave1 -> o
        __syncthreads();

        // ---- Phase 2 (redundant per wave): c1/h1 update ----
        const float gi = act[p][0][j];
        const float gf = act[p][1][j];
        const float gg = act[p][2][j];
        const float go = act[p][3][j];
        c1 = fmaf(gf, c1, gi * gg);
        h1 = go * fast_tanh(c1);

        // ---- LSTM2: 4 dots over lanes 0..50 via butterfly ----
        float p0 = wi2[0] * h1;
        float p1 = wi2[1] * h1;
        float p2 = wi2[2] * h1;
        float p3 = wi2[3] * h1;
#pragma unroll
        for (int m = 1; m < WAVE; m <<= 1) {
            p0 += __shfl_xor(p0, m, WAVE);
            p1 += __shfl_xor(p1, m, WAVE);
            p2 += __shfl_xor(p2, m, WAVE);
            p3 += __shfl_xor(p3, m, WAVE);
        }
        const float g2i = fast_sigmoid(fmaf(whh2[0], h2, b2[0] + p0));
        const float g2f = fast_sigmoid(fmaf(whh2[1], h2, b2[1] + p1));
        const float g2g = fast_tanh  (fmaf(whh2[2], h2, b2[2] + p2));
        const float g2o = fast_sigmoid(fmaf(whh2[3], h2, b2[3] + p3));
        c2 = fmaf(g2f, c2, g2i * g2g);
        h2 = g2o * fast_tanh(c2);

        if (tid == 0) orow[t] = h2;
        xc = xn;
    }
}

extern "C" void kernel_launch(void* const* d_in, const int* in_sizes, int n_in,
                              void* d_out, int out_size, void* d_ws, size_t ws_size,
                              hipStream_t stream) {
    const float* input = (const float*)d_in[0];
    const float* W_ih1 = (const float*)d_in[1];
    const float* W_hh1 = (const float*)d_in[2];
    const float* b_ih1 = (const float*)d_in[3];
    const float* b_hh1 = (const float*)d_in[4];
    const float* W_ih2 = (const float*)d_in[5];
    const float* W_hh2 = (const float*)d_in[6];
    const float* b_ih2 = (const float*)d_in[7];
    const float* b_hh2 = (const float*)d_in[8];
    float* out = (float*)d_out;

    const int B  = 2048;
    const int T  = in_sizes[0] / B;      // 1024
    const int TF = out_size   / B;       // 1088

    lstm_seq<<<dim3(B), dim3(128), 0, stream>>>(
        input, W_ih1, W_hh1, b_ih1, b_hh1, W_ih2, W_hh2, b_ih2, b_hh2,
        out, T, TF);
}

// Round 3
// 2175.524 us; speedup vs baseline: 1.1284x; 1.1284x over previous
//
#include <hip/hip_runtime.h>

// 2-layer LSTM recurrence, B=2048, T=1024 + future=64. One batch element per
// 128-thread block (2 waves). Lane j of wave q owns LSTM1 gate rows
// {q==0: i(j), g(102+j); q==1: f(51+j), o(153+j)}; the two rows' W_hh1 weights
// are interleaved per-lane as v2f wAB[51] so the dot runs as v_pk_fma_f32.
//
// KEY FIX (R3): the compiler refused to keep the 102 weight VGPRs resident
// (R1: VGPR=64, R2: VGPR=68 — it rematerialized uncoalesced global loads
// inside the t-loop; that was the real bottleneck both rounds). Each weight
// register is now pinned via an empty `asm volatile("" : "+v"(w))` — an asm
// def cannot be rematerialized or folded back into a load, so the values MUST
// stay in VGPRs (budget 168 at 3 waves/SIMD, ~140 live).
//
// Also: LSTM2's 4 wave-reductions moved from ds_swizzle butterfly (24 DS ops
// on the per-CU-shared LDS pipe) to DPP v_add reduction (VALU pipe, 4 units
// per CU): row_shr 1/2/4/8 + row_bcast 15/31, total in lane 63.

#define H1N 51
#define WAVE 64

typedef float v2f __attribute__((ext_vector_type(2)));

__device__ __forceinline__ float fast_sigmoid(float x) {
    return __builtin_amdgcn_rcpf(1.0f + __expf(-x));
}
__device__ __forceinline__ float fast_tanh(float x) {
    float e = __expf(2.0f * x);
    return 1.0f - 2.0f * __builtin_amdgcn_rcpf(e + 1.0f);
}

// Canonical GCN/CDNA DPP wave64 sum-reduce; result broadcast from lane 63.
// old=0 + bound_ctrl=false => masked/OOB lanes contribute +0.
template<int CTRL, int RM, int BM>
__device__ __forceinline__ float dpp_add(float a) {
    int t = __builtin_amdgcn_update_dpp(0, __float_as_int(a), CTRL, RM, BM, false);
    return a + __int_as_float(t);
}
__device__ __forceinline__ float wave_sum_bcast(float a) {
    a = dpp_add<0x111, 0xf, 0xf>(a);  // row_shr:1
    a = dpp_add<0x112, 0xf, 0xf>(a);  // row_shr:2
    a = dpp_add<0x114, 0xf, 0xe>(a);  // row_shr:4
    a = dpp_add<0x118, 0xf, 0xc>(a);  // row_shr:8
    a = dpp_add<0x142, 0xa, 0xf>(a);  // row_bcast:15
    a = dpp_add<0x143, 0xc, 0xf>(a);  // row_bcast:31
    return __int_as_float(__builtin_amdgcn_readlane(__float_as_int(a), 63));
}

__global__ __launch_bounds__(128, 3)
void lstm_seq(const float* __restrict__ input,   // [B, T]
              const float* __restrict__ W_ih1,   // [204, 1]
              const float* __restrict__ W_hh1,   // [204, 51]
              const float* __restrict__ b_ih1,   // [204]
              const float* __restrict__ b_hh1,   // [204]
              const float* __restrict__ W_ih2,   // [4, 51]
              const float* __restrict__ W_hh2,   // [4, 1]
              const float* __restrict__ b_ih2,   // [4]
              const float* __restrict__ b_hh2,   // [4]
              float* __restrict__ out,           // [B, T+F]
              int T, int TF)
{
    const int tid = threadIdx.x;
    const int wv  = tid >> 6;          // wave id: 0 or 1
    const int j   = tid & (WAVE - 1);  // lane id
    const bool jv = (j < H1N);
    const int b   = blockIdx.x;

    // Gate rows owned by this lane (gate order i,f,g,o):
    const int rowA = wv ? (H1N + j)   : j;            // f : i
    const int rowB = wv ? (3*H1N + j) : (2*H1N + j);  // o : g

    // Interleaved per-lane weights: wAB[k] = (W_hh1[rowA][k], W_hh1[rowB][k]).
    v2f wAB[H1N];
#pragma unroll
    for (int k = 0; k < H1N; ++k) {
        wAB[k].x = jv ? W_hh1[rowA*H1N + k] : 0.0f;
        wAB[k].y = jv ? W_hh1[rowB*H1N + k] : 0.0f;
    }
    v2f bAB, wxAB;
    bAB.x  = jv ? (b_ih1[rowA] + b_hh1[rowA]) : 0.0f;
    bAB.y  = jv ? (b_ih1[rowB] + b_hh1[rowB]) : 0.0f;
    wxAB.x = jv ? W_ih1[rowA] : 0.0f;
    wxAB.y = jv ? W_ih1[rowB] : 0.0f;

    float wi2[4];
#pragma unroll
    for (int q = 0; q < 4; ++q) wi2[q] = jv ? W_ih2[q*H1N + j] : 0.0f;
    float whh2[4], b2[4];  // thread-uniform -> SGPRs
#pragma unroll
    for (int q = 0; q < 4; ++q) { whh2[q] = W_hh2[q]; b2[q] = b_ih2[q] + b_hh2[q]; }

    // --- PIN the hot-loop weights into VGPRs (defeat rematerialization). ---
#pragma unroll
    for (int k = 0; k < H1N; ++k) asm volatile("" : "+v"(wAB[k]));
    asm volatile("" : "+v"(bAB));
    asm volatile("" : "+v"(wxAB));
#pragma unroll
    for (int q = 0; q < 4; ++q) asm volatile("" : "+v"(wi2[q]));

    // Gate-major, lane-consecutive => conflict-free. [parity][gate][unit]
    __shared__ float act[2][4][WAVE];

    float h1 = 0.0f, c1 = 0.0f, h2 = 0.0f, c2 = 0.0f;

    const float* __restrict__ xrow = input + (long)b * T;
    float*       __restrict__ orow = out   + (long)b * TF;

    auto step = [&](float x, int p) {
        // ---- Phase 1: packed gate dots; h1 broadcast via v_readlane ----
        v2f accE = bAB + wxAB * x;
        v2f accO = {0.0f, 0.0f};
#pragma unroll
        for (int k = 0; k + 1 < H1N; k += 2) {
            float hE = __int_as_float(__builtin_amdgcn_readlane(__float_as_int(h1), k));
            float hO = __int_as_float(__builtin_amdgcn_readlane(__float_as_int(h1), k + 1));
            accE += wAB[k]     * hE;   // v_pk_fma_f32
            accO += wAB[k + 1] * hO;
        }
        {
            float hL = __int_as_float(__builtin_amdgcn_readlane(__float_as_int(h1), H1N - 1));
            accE += wAB[H1N - 1] * hL;
        }
        const v2f acc = accE + accO;

        float aA, aB;
        if (wv == 0) { aA = fast_sigmoid(acc.x); aB = fast_tanh(acc.y); }    // i, g
        else         { aA = fast_sigmoid(acc.x); aB = fast_sigmoid(acc.y); } // f, o

        act[p][wv][j]     = aA;   // wave0 -> i, wave1 -> f
        act[p][wv + 2][j] = aB;   // wave0 -> g, wave1 -> o
        __syncthreads();

        // ---- Phase 2 (redundant per wave): c1/h1 update ----
        const float gi = act[p][0][j];
        const float gf = act[p][1][j];
        const float gg = act[p][2][j];
        const float go = act[p][3][j];
        c1 = fmaf(gf, c1, gi * gg);
        h1 = go * fast_tanh(c1);

        // ---- LSTM2 (H2=1): 4 dots over lanes via DPP reduce (VALU pipe) ----
        const float p0 = wave_sum_bcast(wi2[0] * h1);
        const float p1 = wave_sum_bcast(wi2[1] * h1);
        const float p2 = wave_sum_bcast(wi2[2] * h1);
        const float p3 = wave_sum_bcast(wi2[3] * h1);
        const float g2i = fast_sigmoid(fmaf(whh2[0], h2, b2[0] + p0));
        const float g2f = fast_sigmoid(fmaf(whh2[1], h2, b2[1] + p1));
        const float g2g = fast_tanh  (fmaf(whh2[2], h2, b2[2] + p2));
        const float g2o = fast_sigmoid(fmaf(whh2[3], h2, b2[3] + p3));
        c2 = fmaf(g2f, c2, g2i * g2g);
        h2 = g2o * fast_tanh(c2);
    };

    // Warm phase: x streamed from input (uniform s_load, prefetched 1 ahead).
    float xc = xrow[0];
    for (int t = 0; t < T; ++t) {
        const int tn = (t + 1 < T) ? (t + 1) : (T - 1);
        const float xn = xrow[tn];
        step(xc, t & 1);
        if (tid == 0) orow[t] = h2;
        xc = xn;
    }
    // Future phase: x = h2 feedback.
    for (int t = T; t < TF; ++t) {
        step(h2, t & 1);
        if (tid == 0) orow[t] = h2;
    }
}

extern "C" void kernel_launch(void* const* d_in, const int* in_sizes, int n_in,
                              void* d_out, int out_size, void* d_ws, size_t ws_size,
                              hipStream_t stream) {
    const float* input = (const float*)d_in[0];
    const float* W_ih1 = (const float*)d_in[1];
    const float* W_hh1 = (const float*)d_in[2];
    const float* b_ih1 = (const float*)d_in[3];
    const float* b_hh1 = (const float*)d_in[4];
    const float* W_ih2 = (const float*)d_in[5];
    const float* W_hh2 = (const float*)d_in[6];
    const float* b_ih2 = (const float*)d_in[7];
    const float* b_hh2 = (const float*)d_in[8];
    float* out = (float*)d_out;

    const int B  = 2048;
    const int T  = in_sizes[0] / B;      // 1024
    const int TF = out_size   / B;       // 1088

    lstm_seq<<<dim3(B), dim3(128), 0, stream>>>(
        input, W_ih1, W_hh1, b_ih1, b_hh1, W_ih2, W_hh2, b_ih2, b_hh2,
        out, T, TF);
}

// Round 5
// 1475.820 us; speedup vs baseline: 1.6634x; 1.4741x over previous
//
#include <hip/hip_runtime.h>

// R5 = R4 with the writelane fixed (intrinsic unavailable on this ROCm).
// One WAVE per sequence. Block = 64 threads = 1 wave, grid = 2048 blocks
// (one per batch element) = exactly 8 blocks/CU at 2 waves/SIMD.
//
// Lane j owns ALL FOUR LSTM1 gate rows of hidden unit j: rows j (i), 51+j (f),
// 102+j (g), 153+j (o). Weights are packed as v2f w_if[51], w_go[51] so the
// recurrent matvec is: per k, ONE v_readlane h1[k] feeding TWO v_pk_fma_f32
// (204 MACs per 51 readlanes — broadcast overhead halved vs R1-R3).
// The c1/h1 update is LANE-LOCAL: no LDS, no barriers, nothing cross-wave
// except the readlane broadcast and the LSTM2 DPP reduction.
//
// x input and h2 output move through lane-indexed register buffers (xbuf/obuf)
// with one coalesced global access per 64 steps. h2 is wave-uniform (built
// from broadcast reductions), so obuf packing is a predicated move
// (v_cmp + v_cndmask), no writelane needed.
//
// R1-R3 lesson: the allocator refused to keep the weight array in arch VGPRs
// (VGPR_Count stuck at 64-68; weights shuttled from AGPR/scratch every use =
// the real bottleneck). Here the weight set is the kernel's entire register
// story (~240 of the 256-cap at __launch_bounds__(64,2)) and every value is
// pinned with an asm reg constraint after init.

#define H1N 51
#define WAVE 64

typedef float v2f __attribute__((ext_vector_type(2)));

__device__ __forceinline__ float fast_sigmoid(float x) {
    return __builtin_amdgcn_rcpf(1.0f + __expf(-x));
}
__device__ __forceinline__ float fast_tanh(float x) {
    float e = __expf(2.0f * x);
    return 1.0f - 2.0f * __builtin_amdgcn_rcpf(e + 1.0f);
}
__device__ __forceinline__ float rdlane(float v, int k) {
    return __int_as_float(__builtin_amdgcn_readlane(__float_as_int(v), k));
}

// DPP wave64 sum-reduce; result valid in lane 63, broadcast via readlane.
template<int CTRL, int RM, int BM>
__device__ __forceinline__ float dpp_add(float a) {
    int t = __builtin_amdgcn_update_dpp(0, __float_as_int(a), CTRL, RM, BM, false);
    return a + __int_as_float(t);
}
__device__ __forceinline__ float wave_sum_bcast(float a) {
    a = dpp_add<0x111, 0xf, 0xf>(a);  // row_shr:1
    a = dpp_add<0x112, 0xf, 0xf>(a);  // row_shr:2
    a = dpp_add<0x114, 0xf, 0xe>(a);  // row_shr:4
    a = dpp_add<0x118, 0xf, 0xc>(a);  // row_shr:8
    a = dpp_add<0x142, 0xa, 0xf>(a);  // row_bcast:15
    a = dpp_add<0x143, 0xc, 0xf>(a);  // row_bcast:31
    return rdlane(a, 63);
}

__global__ __launch_bounds__(WAVE, 2)
void lstm_seq(const float* __restrict__ input,   // [B, T]
              const float* __restrict__ W_ih1,   // [204, 1]
              const float* __restrict__ W_hh1,   // [204, 51]
              const float* __restrict__ b_ih1,   // [204]
              const float* __restrict__ b_hh1,   // [204]
              const float* __restrict__ W_ih2,   // [4, 51]
              const float* __restrict__ W_hh2,   // [4, 1]
              const float* __restrict__ b_ih2,   // [4]
              const float* __restrict__ b_hh2,   // [4]
              float* __restrict__ out,           // [B, T+F]
              int T, int TF)
{
    const int j  = threadIdx.x;          // lane = hidden unit
    const bool jv = (j < H1N);
    const int jj = jv ? j : 0;           // clamped (avoid OOB reads)
    const float m = jv ? 1.0f : 0.0f;    // zero-mask for pad lanes
    const int b  = blockIdx.x;           // sequence

    const int r_i = jj, r_f = H1N + jj, r_g = 2*H1N + jj, r_o = 3*H1N + jj;

    // Per-lane weights: w_if[k] = (W_hh1[i-row][k], W_hh1[f-row][k]), etc.
    v2f w_if[H1N], w_go[H1N];
#pragma unroll
    for (int k = 0; k < H1N; ++k) {
        w_if[k].x = m * W_hh1[r_i*H1N + k];
        w_if[k].y = m * W_hh1[r_f*H1N + k];
        w_go[k].x = m * W_hh1[r_g*H1N + k];
        w_go[k].y = m * W_hh1[r_o*H1N + k];
    }
    v2f b_if, b_go, wx_if, wx_go;
    b_if.x  = m * (b_ih1[r_i] + b_hh1[r_i]);
    b_if.y  = m * (b_ih1[r_f] + b_hh1[r_f]);
    b_go.x  = m * (b_ih1[r_g] + b_hh1[r_g]);
    b_go.y  = m * (b_ih1[r_o] + b_hh1[r_o]);
    wx_if.x = m * W_ih1[r_i];
    wx_if.y = m * W_ih1[r_f];
    wx_go.x = m * W_ih1[r_g];
    wx_go.y = m * W_ih1[r_o];

    // LSTM2 input weights: lane j holds W_ih2[q][j] (0 for pad lanes).
    float wi2_0 = m * W_ih2[0*H1N + jj];
    float wi2_1 = m * W_ih2[1*H1N + jj];
    float wi2_2 = m * W_ih2[2*H1N + jj];
    float wi2_3 = m * W_ih2[3*H1N + jj];
    // Thread-uniform scalars (SGPRs).
    const float wh2_0 = W_hh2[0], wh2_1 = W_hh2[1], wh2_2 = W_hh2[2], wh2_3 = W_hh2[3];
    const float b2_0 = b_ih2[0] + b_hh2[0], b2_1 = b_ih2[1] + b_hh2[1];
    const float b2_2 = b_ih2[2] + b_hh2[2], b2_3 = b_ih2[3] + b_hh2[3];

    // Pin everything hot into VGPRs (defeat remat/AGPR-parking).
#pragma unroll
    for (int k = 0; k < H1N; ++k) { asm volatile("" : "+v"(w_if[k])); asm volatile("" : "+v"(w_go[k])); }
    asm volatile("" : "+v"(b_if), "+v"(b_go), "+v"(wx_if), "+v"(wx_go));
    asm volatile("" : "+v"(wi2_0), "+v"(wi2_1), "+v"(wi2_2), "+v"(wi2_3));

    float h1 = 0.0f, c1 = 0.0f, h2 = 0.0f, c2 = 0.0f;

    const float* __restrict__ xrow = input + (long)b * T;
    float*       __restrict__ orow = out   + (long)b * TF;

    float xbuf = 0.0f;  // 64 upcoming x values, lane-indexed
    float obuf = 0.0f;  // 64 produced h2 values, lane-indexed

    for (int t = 0; t < TF; ++t) {
        float x;
        if (t < T) {
            if ((t & 63) == 0) xbuf = xrow[t + j];   // coalesced, once per 64
            x = rdlane(xbuf, t & 63);
        } else {
            x = h2;                                   // future: feed back h2
        }

        // ---- LSTM1: 4-row packed dot; h1 broadcast via readlane ----
        const v2f x2 = {x, x};
        v2f acc_if = b_if + wx_if * x2;
        v2f acc_go = b_go + wx_go * x2;
#pragma unroll
        for (int k = 0; k < H1N; ++k) {
            const float hk = rdlane(h1, k);
            const v2f hk2 = {hk, hk};
            acc_if += w_if[k] * hk2;   // v_pk_fma_f32
            acc_go += w_go[k] * hk2;   // v_pk_fma_f32
        }
        const float gi = fast_sigmoid(acc_if.x);
        const float gf = fast_sigmoid(acc_if.y);
        const float gg = fast_tanh  (acc_go.x);
        const float go = fast_sigmoid(acc_go.y);
        c1 = fmaf(gf, c1, gi * gg);      // lane-local!
        h1 = go * fast_tanh(c1);

        // ---- LSTM2 (H2=1): 4 dots over lanes via DPP reduce ----
        const float p0 = wave_sum_bcast(wi2_0 * h1);
        const float p1 = wave_sum_bcast(wi2_1 * h1);
        const float p2 = wave_sum_bcast(wi2_2 * h1);
        const float p3 = wave_sum_bcast(wi2_3 * h1);
        const float g2i = fast_sigmoid(fmaf(wh2_0, h2, b2_0 + p0));
        const float g2f = fast_sigmoid(fmaf(wh2_1, h2, b2_1 + p1));
        const float g2g = fast_tanh  (fmaf(wh2_2, h2, b2_2 + p2));
        const float g2o = fast_sigmoid(fmaf(wh2_3, h2, b2_3 + p3));
        c2 = fmaf(g2f, c2, g2i * g2g);
        h2 = g2o * fast_tanh(c2);

        // ---- Output: h2 is wave-uniform; pack into lane (t&63) with a
        // predicated move (v_cndmask), flush coalesced once per 64 steps ----
        if (j == (t & 63)) obuf = h2;
        if ((t & 63) == 63) orow[t - 63 + j] = obuf;   // coalesced store
    }
}

extern "C" void kernel_launch(void* const* d_in, const int* in_sizes, int n_in,
                              void* d_out, int out_size, void* d_ws, size_t ws_size,
                              hipStream_t stream) {
    const float* input = (const float*)d_in[0];
    const float* W_ih1 = (const float*)d_in[1];
    const float* W_hh1 = (const float*)d_in[2];
    const float* b_ih1 = (const float*)d_in[3];
    const float* b_hh1 = (const float*)d_in[4];
    const float* W_ih2 = (const float*)d_in[5];
    const float* W_hh2 = (const float*)d_in[6];
    const float* b_ih2 = (const float*)d_in[7];
    const float* b_hh2 = (const float*)d_in[8];
    float* out = (float*)d_out;

    const int B  = 2048;
    const int T  = in_sizes[0] / B;      // 1024  (multiple of 64)
    const int TF = out_size   / B;       // 1088  (multiple of 64)

    lstm_seq<<<dim3(B), dim3(WAVE), 0, stream>>>(
        input, W_ih1, W_hh1, b_ih1, b_hh1, W_ih2, W_hh2, b_ih2, b_hh2,
        out, T, TF);
}

// Round 6
// 1442.093 us; speedup vs baseline: 1.7023x; 1.0234x over previous
//
#include <hip/hip_runtime.h>

// R6: one WAVE per sequence (2048 one-wave blocks = 8 waves/CU = 2/SIMD).
// Lane j owns all four LSTM1 gate rows of hidden unit j. Weights per gate are
// packed as dual-k pairs wI/wF/wG/wO[26] (v2f over k=2kk,2kk+1, padded to 52
// with zeros) so the recurrent matvec is, per k-pair: 2 v_readlane + ONE
// broadcast pair hp={h[2kk],h[2kk+1]} + 4 v_pk_fma_f32. Lane-local c1/h1.
// LSTM2 (H2=1) via 4-way interleaved DPP tree reduction. No LDS, no barriers.
//
// THE fix this round: R5's allocator capped arch VGPRs at 128 (then shuttled
// the 204 weight floats through AGPR/scratch every step — the measured ~2x
// VALU overhead). __launch_bounds__(64,2) only sets a MIN waves/EU; LLVM
// still chases higher occupancy and squeezes registers. amdgpu_waves_per_eu(2,2)
// pins min=max=2 so a 256-VGPR wave is costless to the allocator's model:
// 208 weight regs + ~40 working set fit resident. 2 waves x 248 <= 512/SIMD.

#define H1N 51
#define NP  26   // k-pairs, covers k=0..51 (k=51 weight = 0)
#define WAVE 64

typedef float v2f __attribute__((ext_vector_type(2)));

__device__ __forceinline__ float fast_sigmoid(float x) {
    return __builtin_amdgcn_rcpf(1.0f + __expf(-x));
}
__device__ __forceinline__ float fast_tanh(float x) {
    float e = __expf(2.0f * x);
    return 1.0f - 2.0f * __builtin_amdgcn_rcpf(e + 1.0f);
}
__device__ __forceinline__ float rdlane(float v, int k) {
    return __int_as_float(__builtin_amdgcn_readlane(__float_as_int(v), k));
}

// One DPP reduction stage applied to 4 values (keeps 4-way ILP; the serial
// dependency is only stage-to-stage).
template<int CTRL, int RM, int BM>
__device__ __forceinline__ void dpp_stage4(float& a, float& b, float& c, float& d) {
    int ta = __builtin_amdgcn_update_dpp(0, __float_as_int(a), CTRL, RM, BM, false);
    int tb = __builtin_amdgcn_update_dpp(0, __float_as_int(b), CTRL, RM, BM, false);
    int tc = __builtin_amdgcn_update_dpp(0, __float_as_int(c), CTRL, RM, BM, false);
    int td = __builtin_amdgcn_update_dpp(0, __float_as_int(d), CTRL, RM, BM, false);
    a += __int_as_float(ta); b += __int_as_float(tb);
    c += __int_as_float(tc); d += __int_as_float(td);
}

__global__ __attribute__((amdgpu_flat_work_group_size(64, 64),
                          amdgpu_waves_per_eu(2, 2)))
void lstm_seq(const float* __restrict__ input,   // [B, T]
              const float* __restrict__ W_ih1,   // [204, 1]
              const float* __restrict__ W_hh1,   // [204, 51]
              const float* __restrict__ b_ih1,   // [204]
              const float* __restrict__ b_hh1,   // [204]
              const float* __restrict__ W_ih2,   // [4, 51]
              const float* __restrict__ W_hh2,   // [4, 1]
              const float* __restrict__ b_ih2,   // [4]
              const float* __restrict__ b_hh2,   // [4]
              float* __restrict__ out,           // [B, T+F]
              int T, int TF)
{
    const int j   = threadIdx.x;          // lane = hidden unit
    const bool jv = (j < H1N);
    const int jj  = jv ? j : 0;           // clamped (no OOB)
    const float m = jv ? 1.0f : 0.0f;     // pad-lane mask
    const int b   = blockIdx.x;           // sequence

    const int r_i = jj, r_f = H1N + jj, r_g = 2*H1N + jj, r_o = 3*H1N + jj;

    // Dual-k packed weights: wI[kk] = (W_i[2kk], W_i[2kk+1]), zero-padded.
    v2f wI[NP], wF[NP], wG[NP], wO[NP];
#pragma unroll
    for (int kk = 0; kk < NP; ++kk) {
        const int k0 = 2*kk, k1 = 2*kk + 1;
        const float m0 = (k0 < H1N) ? m : 0.0f;
        const float m1 = (k1 < H1N) ? m : 0.0f;
        const int c0 = (k0 < H1N) ? k0 : 0, c1i = (k1 < H1N) ? k1 : 0;
        wI[kk].x = m0 * W_hh1[r_i*H1N + c0];  wI[kk].y = m1 * W_hh1[r_i*H1N + c1i];
        wF[kk].x = m0 * W_hh1[r_f*H1N + c0];  wF[kk].y = m1 * W_hh1[r_f*H1N + c1i];
        wG[kk].x = m0 * W_hh1[r_g*H1N + c0];  wG[kk].y = m1 * W_hh1[r_g*H1N + c1i];
        wO[kk].x = m0 * W_hh1[r_o*H1N + c0];  wO[kk].y = m1 * W_hh1[r_o*H1N + c1i];
    }
    const float b_i = m * (b_ih1[r_i] + b_hh1[r_i]);
    const float b_f = m * (b_ih1[r_f] + b_hh1[r_f]);
    const float b_g = m * (b_ih1[r_g] + b_hh1[r_g]);
    const float b_o = m * (b_ih1[r_o] + b_hh1[r_o]);
    const float wx_i = m * W_ih1[r_i];
    const float wx_f = m * W_ih1[r_f];
    const float wx_g = m * W_ih1[r_g];
    const float wx_o = m * W_ih1[r_o];

    // LSTM2 input weights: lane j holds W_ih2[q][j] (0 on pad lanes).
    float wi2_0 = m * W_ih2[0*H1N + jj];
    float wi2_1 = m * W_ih2[1*H1N + jj];
    float wi2_2 = m * W_ih2[2*H1N + jj];
    float wi2_3 = m * W_ih2[3*H1N + jj];
    // Thread-uniform scalars (SGPRs).
    const float wh2_0 = W_hh2[0], wh2_1 = W_hh2[1], wh2_2 = W_hh2[2], wh2_3 = W_hh2[3];
    const float b2_0 = b_ih2[0] + b_hh2[0], b2_1 = b_ih2[1] + b_hh2[1];
    const float b2_2 = b_ih2[2] + b_hh2[2], b2_3 = b_ih2[3] + b_hh2[3];

    // Pin weight values into v-regs once (blocks remat-from-global).
#pragma unroll
    for (int kk = 0; kk < NP; ++kk) {
        asm volatile("" : "+v"(wI[kk]), "+v"(wF[kk]), "+v"(wG[kk]), "+v"(wO[kk]));
    }
    asm volatile("" : "+v"(wi2_0), "+v"(wi2_1), "+v"(wi2_2), "+v"(wi2_3));

    float h1 = 0.0f, c1 = 0.0f, h2 = 0.0f, c2 = 0.0f;

    const float* __restrict__ xrow = input + (long)b * T;
    float*       __restrict__ orow = out   + (long)b * TF;

    float xbuf = 0.0f;  // 64 upcoming x values, lane-indexed
    float obuf = 0.0f;  // 64 produced h2 values, lane-indexed

    for (int t = 0; t < TF; ++t) {
        float x;
        if (t < T) {
            if ((t & 63) == 0) xbuf = xrow[t + j];   // coalesced, once per 64
            x = rdlane(xbuf, t & 63);
        } else {
            x = h2;                                   // future: feed back h2
        }

        // ---- LSTM1: dual-k packed matvec (4 gates x 52 k, pad weight 0) ----
        v2f aI = {fmaf(wx_i, x, b_i), 0.0f};
        v2f aF = {fmaf(wx_f, x, b_f), 0.0f};
        v2f aG = {fmaf(wx_g, x, b_g), 0.0f};
        v2f aO = {fmaf(wx_o, x, b_o), 0.0f};
#pragma unroll
        for (int kk = 0; kk < NP; ++kk) {
            const v2f hp = {rdlane(h1, 2*kk), rdlane(h1, 2*kk + 1)};
            aI += wI[kk] * hp;   // v_pk_fma_f32
            aF += wF[kk] * hp;
            aG += wG[kk] * hp;
            aO += wO[kk] * hp;
        }
        const float gi = fast_sigmoid(aI.x + aI.y);
        const float gf = fast_sigmoid(aF.x + aF.y);
        const float gg = fast_tanh  (aG.x + aG.y);
        const float go = fast_sigmoid(aO.x + aO.y);
        c1 = fmaf(gf, c1, gi * gg);      // lane-local
        h1 = go * fast_tanh(c1);

        // ---- LSTM2 (H2=1): 4 reductions, 4-way interleaved DPP tree ----
        float p0 = wi2_0 * h1, p1 = wi2_1 * h1, p2 = wi2_2 * h1, p3 = wi2_3 * h1;
        dpp_stage4<0x111, 0xf, 0xf>(p0, p1, p2, p3);  // row_shr:1
        dpp_stage4<0x112, 0xf, 0xf>(p0, p1, p2, p3);  // row_shr:2
        dpp_stage4<0x114, 0xf, 0xe>(p0, p1, p2, p3);  // row_shr:4
        dpp_stage4<0x118, 0xf, 0xc>(p0, p1, p2, p3);  // row_shr:8
        dpp_stage4<0x142, 0xa, 0xf>(p0, p1, p2, p3);  // row_bcast:15
        dpp_stage4<0x143, 0xc, 0xf>(p0, p1, p2, p3);  // row_bcast:31
        p0 = rdlane(p0, 63); p1 = rdlane(p1, 63);
        p2 = rdlane(p2, 63); p3 = rdlane(p3, 63);

        const float g2i = fast_sigmoid(fmaf(wh2_0, h2, b2_0 + p0));
        const float g2f = fast_sigmoid(fmaf(wh2_1, h2, b2_1 + p1));
        const float g2g = fast_tanh  (fmaf(wh2_2, h2, b2_2 + p2));
        const float g2o = fast_sigmoid(fmaf(wh2_3, h2, b2_3 + p3));
        c2 = fmaf(g2f, c2, g2i * g2g);
        h2 = g2o * fast_tanh(c2);

        // ---- Output: h2 is wave-uniform; predicated pack, flush per 64 ----
        if (j == (t & 63)) obuf = h2;
        if ((t & 63) == 63) orow[t - 63 + j] = obuf;   // coalesced store
    }
}

extern "C" void kernel_launch(void* const* d_in, const int* in_sizes, int n_in,
                              void* d_out, int out_size, void* d_ws, size_t ws_size,
                              hipStream_t stream) {
    const float* input = (const float*)d_in[0];
    const float* W_ih1 = (const float*)d_in[1];
    const float* W_hh1 = (const float*)d_in[2];
    const float* b_ih1 = (const float*)d_in[3];
    const float* b_hh1 = (const float*)d_in[4];
    const float* W_ih2 = (const float*)d_in[5];
    const float* W_hh2 = (const float*)d_in[6];
    const float* b_ih2 = (const float*)d_in[7];
    const float* b_hh2 = (const float*)d_in[8];
    float* out = (float*)d_out;

    const int B  = 2048;
    const int T  = in_sizes[0] / B;      // 1024  (multiple of 64)
    const int TF = out_size   / B;       // 1088  (multiple of 64)

    lstm_seq<<<dim3(B), dim3(WAVE), 0, stream>>>(
        input, W_ih1, W_hh1, b_ih1, b_hh1, W_ih2, W_hh2, b_ih2, b_hh2,
        out, T, TF);
}

// Round 7
// 1349.915 us; speedup vs baseline: 1.8185x; 1.0683x over previous
//
#include <hip/hip_runtime.h>

// R7: one WAVE per sequence (2048 one-wave blocks = 8 waves/CU = 2/SIMD).
// Lane j owns all four LSTM1 gate rows of hidden unit j as dual-k v2f pairs
// wI/wF/wG/wO[26] (k padded to 52 with zero weights).
//
// Residency war, round 3. R5/R6 showed the allocator live-range-splits the
// weight array: pins BEFORE the loop are satisfied once, then master copies
// are parked in AGPR/scratch and shuttled into arch VGPRs at every use
// (~450 extra VALU instr/step = the measured 2.3x over ideal). Fix:
//   (1) empty `asm volatile("" : "+v"(w))` pins INSIDE the t-loop — each
//       weight is "redefined" every iteration, so a parked master copy can't
//       satisfy the next iteration: the value must live in arch VGPRs across
//       the loop. Zero instructions emitted. 208 weight regs + ~40 work < 256.
//   (2) the MAC is hand-issued: h-pair packed into a uint64 (SGPR pair, built
//       by 2 SALU ops off the VALU critical path) and fed to
//       `v_pk_fma_f32 acc, w, s[pair], acc` via inline asm — no splat movs,
//       guaranteed packed-FMA, exactly 1 scalar operand per instr.
// LSTM2 (H2=1) via 4-way interleaved DPP tree. No LDS, no barriers.

#define H1N 51
#define NP  26   // k-pairs, covers k=0..51 (k=51 weight = 0)
#define WAVE 64

typedef float v2f __attribute__((ext_vector_type(2)));

__device__ __forceinline__ float fast_sigmoid(float x) {
    return __builtin_amdgcn_rcpf(1.0f + __expf(-x));
}
__device__ __forceinline__ float fast_tanh(float x) {
    float e = __expf(2.0f * x);
    return 1.0f - 2.0f * __builtin_amdgcn_rcpf(e + 1.0f);
}
__device__ __forceinline__ float rdlane(float v, int k) {
    return __int_as_float(__builtin_amdgcn_readlane(__float_as_int(v), k));
}

template<int CTRL, int RM, int BM>
__device__ __forceinline__ void dpp_stage4(float& a, float& b, float& c, float& d) {
    int ta = __builtin_amdgcn_update_dpp(0, __float_as_int(a), CTRL, RM, BM, false);
    int tb = __builtin_amdgcn_update_dpp(0, __float_as_int(b), CTRL, RM, BM, false);
    int tc = __builtin_amdgcn_update_dpp(0, __float_as_int(c), CTRL, RM, BM, false);
    int td = __builtin_amdgcn_update_dpp(0, __float_as_int(d), CTRL, RM, BM, false);
    a += __int_as_float(ta); b += __int_as_float(tb);
    c += __int_as_float(tc); d += __int_as_float(td);
}

__global__ __attribute__((amdgpu_flat_work_group_size(64, 64),
                          amdgpu_waves_per_eu(2, 2)))
void lstm_seq(const float* __restrict__ input,   // [B, T]
              const float* __restrict__ W_ih1,   // [204, 1]
              const float* __restrict__ W_hh1,   // [204, 51]
              const float* __restrict__ b_ih1,   // [204]
              const float* __restrict__ b_hh1,   // [204]
              const float* __restrict__ W_ih2,   // [4, 51]
              const float* __restrict__ W_hh2,   // [4, 1]
              const float* __restrict__ b_ih2,   // [4]
              const float* __restrict__ b_hh2,   // [4]
              float* __restrict__ out,           // [B, T+F]
              int T, int TF)
{
    const int j   = threadIdx.x;          // lane = hidden unit
    const bool jv = (j < H1N);
    const int jj  = jv ? j : 0;           // clamped (no OOB)
    const float m = jv ? 1.0f : 0.0f;     // pad-lane mask
    const int b   = blockIdx.x;           // sequence

    const int r_i = jj, r_f = H1N + jj, r_g = 2*H1N + jj, r_o = 3*H1N + jj;

    // Dual-k packed weights: wI[kk] = (W_i[2kk], W_i[2kk+1]), zero-padded.
    v2f wI[NP], wF[NP], wG[NP], wO[NP];
#pragma unroll
    for (int kk = 0; kk < NP; ++kk) {
        const int k0 = 2*kk, k1 = 2*kk + 1;
        const float m0 = (k0 < H1N) ? m : 0.0f;
        const float m1 = (k1 < H1N) ? m : 0.0f;
        const int c0 = (k0 < H1N) ? k0 : 0, c1i = (k1 < H1N) ? k1 : 0;
        wI[kk].x = m0 * W_hh1[r_i*H1N + c0];  wI[kk].y = m1 * W_hh1[r_i*H1N + c1i];
        wF[kk].x = m0 * W_hh1[r_f*H1N + c0];  wF[kk].y = m1 * W_hh1[r_f*H1N + c1i];
        wG[kk].x = m0 * W_hh1[r_g*H1N + c0];  wG[kk].y = m1 * W_hh1[r_g*H1N + c1i];
        wO[kk].x = m0 * W_hh1[r_o*H1N + c0];  wO[kk].y = m1 * W_hh1[r_o*H1N + c1i];
    }
    const float b_i = m * (b_ih1[r_i] + b_hh1[r_i]);
    const float b_f = m * (b_ih1[r_f] + b_hh1[r_f]);
    const float b_g = m * (b_ih1[r_g] + b_hh1[r_g]);
    const float b_o = m * (b_ih1[r_o] + b_hh1[r_o]);
    const float wx_i = m * W_ih1[r_i];
    const float wx_f = m * W_ih1[r_f];
    const float wx_g = m * W_ih1[r_g];
    const float wx_o = m * W_ih1[r_o];

    // LSTM2 input weights: lane j holds W_ih2[q][j] (0 on pad lanes).
    float wi2_0 = m * W_ih2[0*H1N + jj];
    float wi2_1 = m * W_ih2[1*H1N + jj];
    float wi2_2 = m * W_ih2[2*H1N + jj];
    float wi2_3 = m * W_ih2[3*H1N + jj];
    // Thread-uniform scalars (SGPRs).
    const float wh2_0 = W_hh2[0], wh2_1 = W_hh2[1], wh2_2 = W_hh2[2], wh2_3 = W_hh2[3];
    const float b2_0 = b_ih2[0] + b_hh2[0], b2_1 = b_ih2[1] + b_hh2[1];
    const float b2_2 = b_ih2[2] + b_hh2[2], b2_3 = b_ih2[3] + b_hh2[3];

    float h1 = 0.0f, c1 = 0.0f, h2 = 0.0f, c2 = 0.0f;

    const float* __restrict__ xrow = input + (long)b * T;
    float*       __restrict__ orow = out   + (long)b * TF;

    float xbuf = 0.0f;  // 64 upcoming x values, lane-indexed
    float obuf = 0.0f;  // 64 produced h2 values, lane-indexed

    for (int t = 0; t < TF; ++t) {
        // ---- In-loop residency pins: "redefine" every weight each iter so a
        // parked AGPR/scratch master copy can't serve the next iteration.
        // Emits NOTHING; forces arch-VGPR residency across the loop. ----
#pragma unroll
        for (int kk = 0; kk < NP; ++kk)
            asm volatile("" : "+v"(wI[kk]), "+v"(wF[kk]), "+v"(wG[kk]), "+v"(wO[kk]));
        asm volatile("" : "+v"(wi2_0), "+v"(wi2_1), "+v"(wi2_2), "+v"(wi2_3));

        float x;
        if (t < T) {
            if ((t & 63) == 0) xbuf = xrow[t + j];   // coalesced, once per 64
            x = rdlane(xbuf, t & 63);
        } else {
            x = h2;                                   // future: feed back h2
        }

        // ---- LSTM1: dual-k packed matvec, h-pair via SGPR-pair operand ----
        v2f aI = {fmaf(wx_i, x, b_i), 0.0f};
        v2f aF = {fmaf(wx_f, x, b_f), 0.0f};
        v2f aG = {fmaf(wx_g, x, b_g), 0.0f};
        v2f aO = {fmaf(wx_o, x, b_o), 0.0f};
#pragma unroll
        for (int kk = 0; kk < NP; ++kk) {
            // Pack (h[2kk], h[2kk+1]) into an SGPR pair: low 32 = .x, high = .y.
            const unsigned int hlo =
                (unsigned int)__builtin_amdgcn_readlane(__float_as_int(h1), 2*kk);
            const unsigned int hhi =
                (unsigned int)__builtin_amdgcn_readlane(__float_as_int(h1), 2*kk + 1);
            const unsigned long long hp =
                ((unsigned long long)hhi << 32) | (unsigned long long)hlo;
            asm("v_pk_fma_f32 %0, %4, %8, %0\n\t"
                "v_pk_fma_f32 %1, %5, %8, %1\n\t"
                "v_pk_fma_f32 %2, %6, %8, %2\n\t"
                "v_pk_fma_f32 %3, %7, %8, %3"
                : "+v"(aI), "+v"(aF), "+v"(aG), "+v"(aO)
                : "v"(wI[kk]), "v"(wF[kk]), "v"(wG[kk]), "v"(wO[kk]), "s"(hp));
        }
        const float gi = fast_sigmoid(aI.x + aI.y);
        const float gf = fast_sigmoid(aF.x + aF.y);
        const float gg = fast_tanh  (aG.x + aG.y);
        const float go = fast_sigmoid(aO.x + aO.y);
        c1 = fmaf(gf, c1, gi * gg);      // lane-local
        h1 = go * fast_tanh(c1);

        // ---- LSTM2 (H2=1): 4 reductions, 4-way interleaved DPP tree ----
        float p0 = wi2_0 * h1, p1 = wi2_1 * h1, p2 = wi2_2 * h1, p3 = wi2_3 * h1;
        dpp_stage4<0x111, 0xf, 0xf>(p0, p1, p2, p3);  // row_shr:1
        dpp_stage4<0x112, 0xf, 0xf>(p0, p1, p2, p3);  // row_shr:2
        dpp_stage4<0x114, 0xf, 0xe>(p0, p1, p2, p3);  // row_shr:4
        dpp_stage4<0x118, 0xf, 0xc>(p0, p1, p2, p3);  // row_shr:8
        dpp_stage4<0x142, 0xa, 0xf>(p0, p1, p2, p3);  // row_bcast:15
        dpp_stage4<0x143, 0xc, 0xf>(p0, p1, p2, p3);  // row_bcast:31
        p0 = rdlane(p0, 63); p1 = rdlane(p1, 63);
        p2 = rdlane(p2, 63); p3 = rdlane(p3, 63);

        const float g2i = fast_sigmoid(fmaf(wh2_0, h2, b2_0 + p0));
        const float g2f = fast_sigmoid(fmaf(wh2_1, h2, b2_1 + p1));
        const float g2g = fast_tanh  (fmaf(wh2_2, h2, b2_2 + p2));
        const float g2o = fast_sigmoid(fmaf(wh2_3, h2, b2_3 + p3));
        c2 = fmaf(g2f, c2, g2i * g2g);
        h2 = g2o * fast_tanh(c2);

        // ---- Output: h2 is wave-uniform; predicated pack, flush per 64 ----
        if (j == (t & 63)) obuf = h2;
        if ((t & 63) == 63) orow[t - 63 + j] = obuf;   // coalesced store
    }
}

extern "C" void kernel_launch(void* const* d_in, const int* in_sizes, int n_in,
                              void* d_out, int out_size, void* d_ws, size_t ws_size,
                              hipStream_t stream) {
    const float* input = (const float*)d_in[0];
    const float* W_ih1 = (const float*)d_in[1];
    const float* W_hh1 = (const float*)d_in[2];
    const float* b_ih1 = (const float*)d_in[3];
    const float* b_hh1 = (const float*)d_in[4];
    const float* W_ih2 = (const float*)d_in[5];
    const float* W_hh2 = (const float*)d_in[6];
    const float* b_ih2 = (const float*)d_in[7];
    const float* b_hh2 = (const float*)d_in[8];
    float* out = (float*)d_out;

    const int B  = 2048;
    const int T  = in_sizes[0] / B;      // 1024  (multiple of 64)
    const int TF = out_size   / B;       // 1088  (multiple of 64)

    lstm_seq<<<dim3(B), dim3(WAVE), 0, stream>>>(
        input, W_ih1, W_hh1, b_ih1, b_hh1, W_ih2, W_hh2, b_ih2, b_hh2,
        out, T, TF);
}

// Round 9
// 1321.135 us; speedup vs baseline: 1.8581x; 1.0218x over previous
//
#include <hip/hip_runtime.h>

// R9 = R8 with the exp builtin name fixed (__builtin_amdgcn_exp2f = 2^x,
// which is exactly what the 1/ln2-pre-scaled domain needs).
//
// One WAVE per sequence (2048 one-wave blocks = 8 waves/CU = 2/SIMD).
// Lane j owns all four LSTM1 gate rows of hidden unit j as dual-k v2f pairs
// wI/wF/wG/wO[26] (k padded to 52 with zero weights).
//
// Residency war, final form. R5-R7 evidence: the RA parks the 208 weight regs
// in AGPRs and shuttles them to arch VGPRs per use (R7: ~735 VALU instr/step
// vs ~290 ideal = 208 accvgpr_read + 208 accvgpr_write — in-loop pins forced
// a ROUND TRIP). Fix: the weights are "+v" OPERANDS OF THE MAC ASM ITSELF.
// Each kk's v_pk_fma block formally redefines the weights it reads, and the
// next iteration reads that def — there is no pin-to-use gap where the RA can
// insert a shuttle. Legal outcomes: 208 resident arch VGPRs (demand ~243 <=
// 256 at waves_per_eu(2,2)) or scratch spill (visible in WRITE_SIZE).
//
// Also: all LSTM weights/biases pre-scaled by 1/ln2 (tanh-input rows by
// 2/ln2) so sigmoid/tanh use v_exp_f32 (2^x) directly: sigmoid(a) in scaled
// domain = rcp(1+2^-a'); tanh = 1-2*rcp(2^a''+1). Saves the 1.4427 muls.
// LSTM2 (H2=1) via 4-way interleaved DPP tree. No LDS, no barriers.

#define H1N 51
#define NP  26   // k-pairs, covers k=0..51 (k=51 weight = 0)
#define WAVE 64

typedef float v2f __attribute__((ext_vector_type(2)));

#define INV_LN2  1.44269504088896340736f
#define INV_LN2X2 2.88539008177792681472f

// Scaled-domain activations: input already multiplied by 1/ln2 (or 2/ln2).
__device__ __forceinline__ float sigmoid_s(float xs) {
    // sigmoid(a) = 1/(1+2^{-a*invln2})
    return __builtin_amdgcn_rcpf(1.0f + __builtin_amdgcn_exp2f(-xs));
}
__device__ __forceinline__ float tanh_s2(float xs2) {
    // tanh(a) = 1 - 2/(2^{a*2invln2}+1)
    float e = __builtin_amdgcn_exp2f(xs2);
    return fmaf(-2.0f, __builtin_amdgcn_rcpf(e + 1.0f), 1.0f);
}
__device__ __forceinline__ float tanh_nat(float x) {   // natural-domain input
    return tanh_s2(x * INV_LN2X2);
}
__device__ __forceinline__ float rdlane(float v, int k) {
    return __int_as_float(__builtin_amdgcn_readlane(__float_as_int(v), k));
}

template<int CTRL, int RM, int BM>
__device__ __forceinline__ void dpp_stage4(float& a, float& b, float& c, float& d) {
    int ta = __builtin_amdgcn_update_dpp(0, __float_as_int(a), CTRL, RM, BM, false);
    int tb = __builtin_amdgcn_update_dpp(0, __float_as_int(b), CTRL, RM, BM, false);
    int tc = __builtin_amdgcn_update_dpp(0, __float_as_int(c), CTRL, RM, BM, false);
    int td = __builtin_amdgcn_update_dpp(0, __float_as_int(d), CTRL, RM, BM, false);
    a += __int_as_float(ta); b += __int_as_float(tb);
    c += __int_as_float(tc); d += __int_as_float(td);
}

__global__ __attribute__((amdgpu_flat_work_group_size(64, 64),
                          amdgpu_waves_per_eu(2, 2)))
void lstm_seq(const float* __restrict__ input,   // [B, T]
              const float* __restrict__ W_ih1,   // [204, 1]
              const float* __restrict__ W_hh1,   // [204, 51]
              const float* __restrict__ b_ih1,   // [204]
              const float* __restrict__ b_hh1,   // [204]
              const float* __restrict__ W_ih2,   // [4, 51]
              const float* __restrict__ W_hh2,   // [4, 1]
              const float* __restrict__ b_ih2,   // [4]
              const float* __restrict__ b_hh2,   // [4]
              float* __restrict__ out,           // [B, T+F]
              int T, int TF)
{
    const int j   = threadIdx.x;          // lane = hidden unit
    const bool jv = (j < H1N);
    const int jj  = jv ? j : 0;           // clamped (no OOB)
    const float m = jv ? 1.0f : 0.0f;     // pad-lane mask
    const int b   = blockIdx.x;           // sequence

    const int r_i = jj, r_f = H1N + jj, r_g = 2*H1N + jj, r_o = 3*H1N + jj;

    // Gate-row scale factors: sigmoid rows 1/ln2, tanh (g) row 2/ln2.
    const float s_i = m * INV_LN2, s_f = m * INV_LN2;
    const float s_g = m * INV_LN2X2, s_o = m * INV_LN2;

    // Dual-k packed, pre-scaled weights (zero-padded at k=51 and pad lanes).
    v2f wI[NP], wF[NP], wG[NP], wO[NP];
#pragma unroll
    for (int kk = 0; kk < NP; ++kk) {
        const int k0 = 2*kk, k1 = 2*kk + 1;
        const float n0 = (k0 < H1N) ? 1.0f : 0.0f;
        const float n1 = (k1 < H1N) ? 1.0f : 0.0f;
        const int c0 = (k0 < H1N) ? k0 : 0, c1i = (k1 < H1N) ? k1 : 0;
        wI[kk].x = s_i * n0 * W_hh1[r_i*H1N + c0];  wI[kk].y = s_i * n1 * W_hh1[r_i*H1N + c1i];
        wF[kk].x = s_f * n0 * W_hh1[r_f*H1N + c0];  wF[kk].y = s_f * n1 * W_hh1[r_f*H1N + c1i];
        wG[kk].x = s_g * n0 * W_hh1[r_g*H1N + c0];  wG[kk].y = s_g * n1 * W_hh1[r_g*H1N + c1i];
        wO[kk].x = s_o * n0 * W_hh1[r_o*H1N + c0];  wO[kk].y = s_o * n1 * W_hh1[r_o*H1N + c1i];
    }
    const float b_i = s_i * (b_ih1[r_i] + b_hh1[r_i]);
    const float b_f = s_f * (b_ih1[r_f] + b_hh1[r_f]);
    const float b_g = s_g * (b_ih1[r_g] + b_hh1[r_g]);
    const float b_o = s_o * (b_ih1[r_o] + b_hh1[r_o]);
    const float wx_i = s_i * W_ih1[r_i];
    const float wx_f = s_f * W_ih1[r_f];
    const float wx_g = s_g * W_ih1[r_g];
    const float wx_o = s_o * W_ih1[r_o];

    // LSTM2 (pre-scaled): lane j holds W_ih2[q][j].
    float wi2_0 = m * INV_LN2   * W_ih2[0*H1N + jj];
    float wi2_1 = m * INV_LN2   * W_ih2[1*H1N + jj];
    float wi2_2 = m * INV_LN2X2 * W_ih2[2*H1N + jj];
    float wi2_3 = m * INV_LN2   * W_ih2[3*H1N + jj];
    // Thread-uniform scalars (SGPRs), pre-scaled.
    const float wh2_0 = INV_LN2*W_hh2[0], wh2_1 = INV_LN2*W_hh2[1];
    const float wh2_2 = INV_LN2X2*W_hh2[2], wh2_3 = INV_LN2*W_hh2[3];
    const float b2_0 = INV_LN2*(b_ih2[0] + b_hh2[0]), b2_1 = INV_LN2*(b_ih2[1] + b_hh2[1]);
    const float b2_2 = INV_LN2X2*(b_ih2[2] + b_hh2[2]), b2_3 = INV_LN2*(b_ih2[3] + b_hh2[3]);

    float h1 = 0.0f, c1 = 0.0f, h2 = 0.0f, c2 = 0.0f;

    const float* __restrict__ xrow = input + (long)b * T;
    float*       __restrict__ orow = out   + (long)b * TF;

    float xbuf = 0.0f;  // 64 upcoming x values, lane-indexed
    float obuf = 0.0f;  // 64 produced h2 values, lane-indexed

    for (int t = 0; t < TF; ++t) {
        // Small per-lane constants: cheap in-loop pin (4 regs; noise).
        asm volatile("" : "+v"(wi2_0), "+v"(wi2_1), "+v"(wi2_2), "+v"(wi2_3));

        float x;
        if (t < T) {
            if ((t & 63) == 0) xbuf = xrow[t + j];   // coalesced, once per 64
            x = rdlane(xbuf, t & 63);
        } else {
            x = h2;                                   // future: feed back h2
        }

        // ---- LSTM1 matvec: h-pair via SGPR pair; WEIGHTS ARE "+v" OPERANDS
        // OF THE MAC so the RA cannot park them between iterations. ----
        v2f aI = {fmaf(wx_i, x, b_i), 0.0f};
        v2f aF = {fmaf(wx_f, x, b_f), 0.0f};
        v2f aG = {fmaf(wx_g, x, b_g), 0.0f};
        v2f aO = {fmaf(wx_o, x, b_o), 0.0f};
#pragma unroll
        for (int kk = 0; kk < NP; ++kk) {
            const unsigned int hlo =
                (unsigned int)__builtin_amdgcn_readlane(__float_as_int(h1), 2*kk);
            const unsigned int hhi =
                (unsigned int)__builtin_amdgcn_readlane(__float_as_int(h1), 2*kk + 1);
            const unsigned long long hp =
                ((unsigned long long)hhi << 32) | (unsigned long long)hlo;
            asm("v_pk_fma_f32 %0, %4, %8, %0\n\t"
                "v_pk_fma_f32 %1, %5, %8, %1\n\t"
                "v_pk_fma_f32 %2, %6, %8, %2\n\t"
                "v_pk_fma_f32 %3, %7, %8, %3"
                : "+v"(aI), "+v"(aF), "+v"(aG), "+v"(aO),
                  "+v"(wI[kk]), "+v"(wF[kk]), "+v"(wG[kk]), "+v"(wO[kk])
                : "s"(hp));
        }
        const float gi = sigmoid_s(aI.x + aI.y);
        const float gf = sigmoid_s(aF.x + aF.y);
        const float gg = tanh_s2 (aG.x + aG.y);
        const float go = sigmoid_s(aO.x + aO.y);
        c1 = fmaf(gf, c1, gi * gg);      // lane-local
        h1 = go * tanh_nat(c1);

        // ---- LSTM2 (H2=1): 4 reductions, 4-way interleaved DPP tree ----
        float p0 = wi2_0 * h1, p1 = wi2_1 * h1, p2 = wi2_2 * h1, p3 = wi2_3 * h1;
        dpp_stage4<0x111, 0xf, 0xf>(p0, p1, p2, p3);  // row_shr:1
        dpp_stage4<0x112, 0xf, 0xf>(p0, p1, p2, p3);  // row_shr:2
        dpp_stage4<0x114, 0xf, 0xe>(p0, p1, p2, p3);  // row_shr:4
        dpp_stage4<0x118, 0xf, 0xc>(p0, p1, p2, p3);  // row_shr:8
        dpp_stage4<0x142, 0xa, 0xf>(p0, p1, p2, p3);  // row_bcast:15
        dpp_stage4<0x143, 0xc, 0xf>(p0, p1, p2, p3);  // row_bcast:31
        p0 = rdlane(p0, 63); p1 = rdlane(p1, 63);
        p2 = rdlane(p2, 63); p3 = rdlane(p3, 63);

        const float g2i = sigmoid_s(fmaf(wh2_0, h2, b2_0 + p0));
        const float g2f = sigmoid_s(fmaf(wh2_1, h2, b2_1 + p1));
        const float g2g = tanh_s2 (fmaf(wh2_2, h2, b2_2 + p2));
        const float g2o = sigmoid_s(fmaf(wh2_3, h2, b2_3 + p3));
        c2 = fmaf(g2f, c2, g2i * g2g);
        h2 = g2o * tanh_nat(c2);

        // ---- Output: h2 is wave-uniform; predicated pack, flush per 64 ----
        if (j == (t & 63)) obuf = h2;
        if ((t & 63) == 63) orow[t - 63 + j] = obuf;   // coalesced store
    }
}

extern "C" void kernel_launch(void* const* d_in, const int* in_sizes, int n_in,
                              void* d_out, int out_size, void* d_ws, size_t ws_size,
                              hipStream_t stream) {
    const float* input = (const float*)d_in[0];
    const float* W_ih1 = (const float*)d_in[1];
    const float* W_hh1 = (const float*)d_in[2];
    const float* b_ih1 = (const float*)d_in[3];
    const float* b_hh1 = (const float*)d_in[4];
    const float* W_ih2 = (const float*)d_in[5];
    const float* W_hh2 = (const float*)d_in[6];
    const float* b_ih2 = (const float*)d_in[7];
    const float* b_hh2 = (const float*)d_in[8];
    float* out = (float*)d_out;

    const int B  = 2048;
    const int T  = in_sizes[0] / B;      // 1024  (multiple of 64)
    const int TF = out_size   / B;       // 1088  (multiple of 64)

    lstm_seq<<<dim3(B), dim3(WAVE), 0, stream>>>(
        input, W_ih1, W_hh1, b_ih1, b_hh1, W_ih2, W_hh2, b_ih2, b_hh2,
        out, T, TF);
}